// Round 22
// baseline (40.119 us; speedup 1.0000x reference)
//
#include <hip/hip_runtime.h>

#define P_TOT 30000
#define NPT   100
#define COUT  64

typedef __attribute__((ext_vector_type(8)))  short bf16x8;
typedef __attribute__((ext_vector_type(16))) float f32x16;

static constexpr float VXf   = 0.16f;
static constexpr float VYf   = 0.16f;
static constexpr float XOFFf = 0.08f;            // VX/2 + 0.0
static constexpr float YOFFf = 0.08f - 39.68f;   // VY/2 + y_min
static constexpr float INV_M = 1.0f / 3000000.0f; // 1/(P*N)
static constexpr float NEGI  = -3.0e38f;

__device__ inline float wred(float v) {           // cold paths (K2, epilogue)
#pragma unroll
  for (int d = 1; d < 64; d <<= 1) v += __shfl_xor(v, d);
  return v;
}

// Hot-path wave sum via DPP (canonical gfx9 reduce):
// quad_perm xor1, xor2; row_half_mirror; row_mirror; bcast15->rows1,3;
// bcast31->rows2,3; total lands in lane 63; readlane broadcasts via SGPR.
__device__ inline float wred_dpp(float v) {
  float t;
  t = __int_as_float(__builtin_amdgcn_update_dpp(0, __float_as_int(v), 0xB1, 0xF, 0xF, true));  v += t; // xor1
  t = __int_as_float(__builtin_amdgcn_update_dpp(0, __float_as_int(v), 0x4E, 0xF, 0xF, true));  v += t; // xor2
  t = __int_as_float(__builtin_amdgcn_update_dpp(0, __float_as_int(v), 0x141, 0xF, 0xF, true)); v += t; // row_half_mirror
  t = __int_as_float(__builtin_amdgcn_update_dpp(0, __float_as_int(v), 0x140, 0xF, 0xF, true)); v += t; // row_mirror
  t = __int_as_float(__builtin_amdgcn_update_dpp(0, __float_as_int(v), 0x142, 0xA, 0xF, true)); v += t; // bcast15
  t = __int_as_float(__builtin_amdgcn_update_dpp(0, __float_as_int(v), 0x143, 0xC, 0xF, true)); v += t; // bcast31
  return __int_as_float(__builtin_amdgcn_readlane(__float_as_int(v), 63));
}

// (bf16(hi) << 16) | bf16(lo)
__device__ inline unsigned pack_bf2(float lo, float hi) {
  return (__float_as_uint(hi) & 0xFFFF0000u) | (__float_as_uint(lo) >> 16);
}

union AF { bf16x8 v; unsigned u[4]; };

// 3-op fold: max + add + fma(sumsq). Paired partials break the add chains.
__device__ inline void fold_full(const f32x16& c, float& zm, float& zs, float& zq) {
  float s0 = 0.f, s1 = 0.f, q0 = 0.f, q1 = 0.f;
#pragma unroll
  for (int r = 0; r < 8; ++r) {
    zm = fmaxf(fmaxf(zm, c[2 * r]), c[2 * r + 1]);
    s0 += c[2 * r];
    s1 += c[2 * r + 1];
    q0 = fmaf(c[2 * r], c[2 * r], q0);
    q1 = fmaf(c[2 * r + 1], c[2 * r + 1], q1);
  }
  zs += s0 + s1;
  zq += q0 + q1;
}

// Masked fold with quad-skip: C-reg quad qd covers rows 8qd..8qd+7 (both
// lane halves); skip it entirely (uniform branch) when 8qd >= rem.
// Pad rows are exactly 0 -> skipping them is safe for zs/zq too.
__device__ inline void fold_mask(const f32x16& c, int thresh, int rem,
                                 float& zm, float& zs, float& zq) {
  float s0 = 0.f, s1 = 0.f, q0 = 0.f, q1 = 0.f;
#pragma unroll
  for (int qd = 0; qd < 4; ++qd) {
    if (8 * qd < rem) {     // wave-uniform (rem = np - 32t)
#pragma unroll
      for (int r = 4 * qd; r < 4 * qd + 4; ++r) {
        const int ro = (r & 3) + 8 * (r >> 2);        // compile-time row offset
        zm = fmaxf(zm, (ro < thresh) ? c[r] : NEGI);  // exclude zero pad rows
        if (r & 1) { s1 += c[r]; q1 = fmaf(c[r], c[r], q1); }
        else       { s0 += c[r]; q0 = fmaf(c[r], c[r], q0); }
      }
    }
  }
  zs += s0 + s1;
  zq += q0 + q1;
}

// One MFMA pair (both channel halves) + fold for a tile.
#define TILE_BODY(U0, U1, TFULL, THRESH, REM)                                   \
  {                                                                             \
    unsigned u0_ = (U0), u1_ = (U1);                                            \
    if (lane >= 32) { u0_ = 0u; u1_ = 0u; }  /* k-group 1 = zero pad */         \
    AF af;                                                                      \
    af.u[0] = u0_; af.u[1] = u1_; af.u[2] = 0; af.u[3] = 0;                     \
    {                                                                           \
      f32x16 c0 = __builtin_amdgcn_mfma_f32_32x32x16_bf16(af.v, bf0.v, z16, 0, 0, 0); \
      if (TFULL) fold_full(c0, zm0, zs0, zq0);                                  \
      else       fold_mask(c0, (THRESH), (REM), zm0, zs0, zq0);                 \
    }                                                                           \
    {                                                                           \
      f32x16 c1 = __builtin_amdgcn_mfma_f32_32x32x16_bf16(af.v, bf1.v, z16, 0, 0, 0); \
      if (TFULL) fold_full(c1, zm1, zs1, zq1);                                  \
      else       fold_mask(c1, (THRESH), (REM), zm1, zs1, zq1);                 \
    }                                                                           \
  }

// K1: r21 structure (LDS-free register A-fragments, prefetch, 4 static tiles,
// in-fold 3-op stats, DPP wave-reduce, quad-skip fold). Grid matched to work:
// nb=1875 -> 7500 waves x exactly 4 pillars (30000=7500*4), all co-resident,
// eliminating the 4-vs-3 pillar imbalance that capped occupancy at ~33%.
// Per-pillar epilogue (r7-verified):
//   ymax = zmax + b ; sum += zs + np*b ; sumsq += zq + b*(2*zs + np*b)
__global__ __launch_bounds__(256) void k1_mfma(
    const float4* __restrict__ feat, const int* __restrict__ npts,
    const int* __restrict__ coords, const float* __restrict__ W,
    float* __restrict__ ymax, float* __restrict__ partials, int nb) {
  const int lane = threadIdx.x & 63;
  const int wv   = threadIdx.x >> 6;
  const int wave_id = blockIdx.x * 4 + wv;
  const int nwaves  = nb * 4;
  const int rbase   = (lane >> 5) * 4;

  // per-channel weights, affine-folded: ce = (w0+w4+w7, w1+w5+w8, w2+w6, w3)
  float wr[9];
#pragma unroll
  for (int i = 0; i < 9; i++) wr[i] = W[lane * 9 + i];
  const float ce0 = wr[0] + wr[4] + wr[7];
  const float ce1 = wr[1] + wr[5] + wr[8];
  const float ce2 = wr[2] + wr[6];
  const float ce3 = wr[3];

  // B fragments: lane -> channel n*32+(lane&31), real k=0..3 in slots u0,u1
  AF bf0, bf1;
  {
    const unsigned p01 = pack_bf2(ce0, ce1);
    const unsigned p23 = pack_bf2(ce2, ce3);
    const int s0 = lane & 31, s1 = 32 + (lane & 31);
    unsigned b0a = (unsigned)__shfl((int)p01, s0);
    unsigned b0b = (unsigned)__shfl((int)p23, s0);
    unsigned b1a = (unsigned)__shfl((int)p01, s1);
    unsigned b1b = (unsigned)__shfl((int)p23, s1);
    if (lane >= 32) { b0a = b0b = b1a = b1b = 0; }
    bf0.u[0] = b0a; bf0.u[1] = b0b; bf0.u[2] = 0; bf0.u[3] = 0;
    bf1.u[0] = b1a; bf1.u[1] = b1b; bf1.u[2] = 0; bf1.u[3] = 0;
  }

  const f32x16 z16 = {0.f};
  float sum = 0.f, sumsq = 0.f;

  // prologue: load pillar wave_id
  int p = wave_id;
  float4 a0 = make_float4(0.f, 0.f, 0.f, 0.f), a1 = a0;
  int np = 1, cx = 0, cy = 0;
  if (p < P_TOT) {
    const float4* fp = feat + (size_t)p * NPT;
    a0 = fp[lane];
    if (lane < 36) a1 = fp[lane + 64];
    np = npts[p];
    cx = coords[p * 4 + 3];
    cy = coords[p * 4 + 2];
  }

  while (p < P_TOT) {
    const int pn = p + nwaves;
    float4 b0 = make_float4(0.f, 0.f, 0.f, 0.f), b1 = b0;
    int npn = 1, cxn = 0, cyn = 0;
    if (pn < P_TOT) {
      const float4* fpn = feat + (size_t)pn * NPT;
      b0 = fpn[lane];
      if (lane < 36) b1 = fpn[lane + 64];
      npn = npts[pn];
      cxn = coords[pn * 4 + 3];
      cyn = coords[pn * 4 + 2];
    }

    // pack to bf16, then mask (rows >= np become 0)
    unsigned pk0 = pack_bf2(a0.x, a0.y), pk1 = pack_bf2(a0.z, a0.w);
    unsigned pk2 = pack_bf2(a1.x, a1.y), pk3 = pack_bf2(a1.z, a1.w);
    if (lane >= np)      { pk0 = 0u; pk1 = 0u; }
    if (lane + 64 >= np) { pk2 = 0u; pk3 = 0u; }

    // cross-lane xyz sums from RAW rows via DPP (reference: ALL 100 rows / np)
    const float sax = wred_dpp(a0.x + a1.x);
    const float say = wred_dpp(a0.y + a1.y);
    const float saz = wred_dpp(a0.z + a1.z);
    const float inv = 1.f / (float)np;
    const float cxc = (float)cx * VXf + XOFFf;
    const float cyc = (float)cy * VYf + YOFFf;
    float b = wr[4] * (sax * inv);
    b = fmaf(wr[5], say * inv, b);
    b = fmaf(wr[6], saz * inv, b);
    b = fmaf(wr[7], cxc, b);
    b = fmaf(wr[8], cyc, b);
    b = -b;

    // z-loop: 4 static tiles, A-fragments from registers (no LDS)
    float zm0 = NEGI, zm1 = NEGI;
    float zs0 = 0.f, zs1 = 0.f, zq0 = 0.f, zq1 = 0.f;

    TILE_BODY(pk0, pk1, (np >= 32), np - rbase, np);             // tile 0
    if (np > 32) {                                               // tile 1
      const unsigned s0 = (unsigned)__shfl_xor((int)pk0, 32);
      const unsigned s1 = (unsigned)__shfl_xor((int)pk1, 32);
      TILE_BODY(s0, s1, (np >= 64), np - 32 - rbase, np - 32);
    }
    if (np > 64) {                                               // tile 2
      TILE_BODY(pk2, pk3, (np >= 96), np - 64 - rbase, np - 64);
    }
    if (np > 96) {                                               // tile 3
      const unsigned s2 = (unsigned)__shfl_xor((int)pk2, 32);
      const unsigned s3 = (unsigned)__shfl_xor((int)pk3, 32);
      TILE_BODY(s2, s3, false, np - 96 - rbase, np - 96);
    }

    // combine row-halves, pick this lane's channel half
    zm0 = fmaxf(zm0, __shfl_xor(zm0, 32));
    zm1 = fmaxf(zm1, __shfl_xor(zm1, 32));
    zs0 += __shfl_xor(zs0, 32);
    zs1 += __shfl_xor(zs1, 32);
    zq0 += __shfl_xor(zq0, 32);
    zq1 += __shfl_xor(zq1, 32);
    const float zm = (lane < 32) ? zm0 : zm1;   // channel = lane
    const float zs = (lane < 32) ? zs0 : zs1;
    const float zq = (lane < 32) ? zq0 : zq1;

    const float npf = (float)np;
    ymax[p * COUT + lane] = zm + b;
    sum   += zs + npf * b;
    sumsq += zq + b * fmaf(npf, b, 2.f * zs);

    p = pn;
    a0 = b0; a1 = b1; np = npn; cx = cxn; cy = cyn;
  }

  // block reduction: 64 sum rows, 64 sumsq rows
  __syncthreads();
  __shared__ float rs[4][64], rq[4][64];
  rs[wv][lane] = sum;
  rq[wv][lane] = sumsq;
  __syncthreads();
  const int t = threadIdx.x;
  if (t < 128) {
    const int c = t & 63;
    float v;
    if (t < 64) v = rs[0][c] + rs[1][c] + rs[2][c] + rs[3][c];
    else        v = rq[0][c] + rq[1][c] + rq[2][c] + rq[3][c];
    partials[(size_t)blockIdx.x * 128 + t] = v;   // coalesced, block-major
  }
}

// K2: 128 blocks (one per moment), 256 threads each -> TLP hides latency
__global__ __launch_bounds__(256) void k2_reduce(
    const float* __restrict__ partials, int nb, float* __restrict__ S) {
  const int m = blockIdx.x;
  float s = 0.f;
  for (int b = threadIdx.x; b < nb; b += 256) s += partials[(size_t)b * 128 + m];
  s = wred(s);
  __shared__ float t4[4];
  if ((threadIdx.x & 63) == 0) t4[threadIdx.x >> 6] = s;
  __syncthreads();
  if (threadIdx.x == 0) S[m] = t4[0] + t4[1] + t4[2] + t4[3];
}

// K3: finish in place on d_out. gamma==1 => scale>0, so max commutes with BN.
__global__ __launch_bounds__(256) void k3_finish(
    const int* __restrict__ npts, const float* __restrict__ S,
    const float* __restrict__ gamma, const float* __restrict__ beta,
    float* __restrict__ out) {
  const int c  = threadIdx.x & 63;
  const int wv = threadIdx.x >> 6;
  const int p  = blockIdx.x * 4 + wv;   // 7500*4 == 30000

  const float mean  = S[c] * INV_M;
  const float var   = S[64 + c] * INV_M - mean * mean;
  const float scale = gamma[c] * rsqrtf(var + 0.001f);
  const float shift = beta[c] - mean * scale;

  const int np = npts[p];
  float v = fmaf(scale, out[p * COUT + c], shift);
  if (np < NPT) v = fmaxf(v, shift);   // padded positions contribute relu(shift)
  out[p * COUT + c] = fmaxf(v, 0.f);
}

extern "C" void kernel_launch(void* const* d_in, const int* in_sizes, int n_in,
                              void* d_out, int out_size, void* d_ws, size_t ws_size,
                              hipStream_t stream) {
  const float4* feat  = (const float4*)d_in[0];
  const int*   npts   = (const int*)d_in[1];
  const int*   coords = (const int*)d_in[2];
  const float* W      = (const float*)d_in[3];
  const float* gamma  = (const float*)d_in[4];
  const float* beta   = (const float*)d_in[5];
  float* out = (float*)d_out;

  // 1875 blocks * 4 waves = 7500 waves, exactly 4 pillars each (no 4-vs-3
  // imbalance), all co-resident at 8 waves/SIMD.
  int nb = 512;
  if (ws_size >= (size_t)(128 + 1875 * 128) * 4) nb = 1875;
  else if (ws_size >= (size_t)(128 + 1024 * 128) * 4) nb = 1024;

  float* S        = (float*)d_ws;   // 128 floats
  float* partials = S + 128;        // nb*128 floats, block-major

  k1_mfma<<<nb, 256, 0, stream>>>(feat, npts, coords, W, out, partials, nb);
  k2_reduce<<<128, 256, 0, stream>>>(partials, nb, S);
  k3_finish<<<P_TOT / 4, 256, 0, stream>>>(npts, S, gamma, beta, out);
}

// Round 23
// 39.783 us; speedup vs baseline: 1.0084x; 1.0084x over previous
//
#include <hip/hip_runtime.h>

#define P_TOT 30000
#define NPT   100
#define COUT  64

typedef __attribute__((ext_vector_type(8)))  short bf16x8;
typedef __attribute__((ext_vector_type(16))) float f32x16;
typedef __attribute__((ext_vector_type(2)))  float f32x2;

static constexpr float VXf   = 0.16f;
static constexpr float VYf   = 0.16f;
static constexpr float XOFFf = 0.08f;            // VX/2 + 0.0
static constexpr float YOFFf = 0.08f - 39.68f;   // VY/2 + y_min
static constexpr float INV_M = 1.0f / 3000000.0f; // 1/(P*N)
static constexpr float NEGI  = -3.0e38f;

__device__ inline float wred(float v) {           // cold paths (K2, epilogue)
#pragma unroll
  for (int d = 1; d < 64; d <<= 1) v += __shfl_xor(v, d);
  return v;
}

// Hot-path wave sum via DPP (canonical gfx9 reduce).
__device__ inline float wred_dpp(float v) {
  float t;
  t = __int_as_float(__builtin_amdgcn_update_dpp(0, __float_as_int(v), 0xB1, 0xF, 0xF, true));  v += t; // xor1
  t = __int_as_float(__builtin_amdgcn_update_dpp(0, __float_as_int(v), 0x4E, 0xF, 0xF, true));  v += t; // xor2
  t = __int_as_float(__builtin_amdgcn_update_dpp(0, __float_as_int(v), 0x141, 0xF, 0xF, true)); v += t; // row_half_mirror
  t = __int_as_float(__builtin_amdgcn_update_dpp(0, __float_as_int(v), 0x140, 0xF, 0xF, true)); v += t; // row_mirror
  t = __int_as_float(__builtin_amdgcn_update_dpp(0, __float_as_int(v), 0x142, 0xA, 0xF, true)); v += t; // bcast15
  t = __int_as_float(__builtin_amdgcn_update_dpp(0, __float_as_int(v), 0x143, 0xC, 0xF, true)); v += t; // bcast31
  return __int_as_float(__builtin_amdgcn_readlane(__float_as_int(v), 63));
}

// (bf16(hi) << 16) | bf16(lo)
__device__ inline unsigned pack_bf2(float lo, float hi) {
  return (__float_as_uint(hi) & 0xFFFF0000u) | (__float_as_uint(lo) >> 16);
}

union AF { bf16x8 v; unsigned u[4]; };
union CU16 { f32x16 v; f32x2 h[8]; };   // view C as 8 adjacent f32 pairs

// Fold with packed-f32 accumulate: max via v_max3 chains (scalar, 1 op per
// 2 values), zs/zq via v_pk_add_f32 / v_pk_fma_f32 on adjacent C pairs.
// Pair lanes (.x=even idx, .y=odd idx) == r21's s0/s1,q0/q1 grouping, so
// results are bitwise identical to the scalar version.
__device__ inline void fold_full(const f32x16& c, float& zm, f32x2& sA, f32x2& qA) {
  CU16 u; u.v = c;
#pragma unroll
  for (int r = 0; r < 8; ++r) {
    zm = fmaxf(fmaxf(zm, u.v[2 * r]), u.v[2 * r + 1]);  // v_max3
    const f32x2 h = u.h[r];
    sA += h;                    // v_pk_add_f32
    qA += h * h;                // v_pk_fma_f32
  }
}

// Masked fold with quad-skip: C-reg quad qd covers rows 8qd..8qd+7 (both
// lane halves); skip it entirely (uniform branch) when 8qd >= rem.
// Pad rows are exactly 0 -> skipping them is safe for zs/zq too.
__device__ inline void fold_mask(const f32x16& c, int thresh, int rem,
                                 float& zm, f32x2& sA, f32x2& qA) {
  CU16 u; u.v = c;
#pragma unroll
  for (int qd = 0; qd < 4; ++qd) {
    if (8 * qd < rem) {     // wave-uniform (rem = np - 32t)
#pragma unroll
      for (int pr = 2 * qd; pr < 2 * qd + 2; ++pr) {
        const int r0 = 2 * pr, r1 = 2 * pr + 1;
        const int ro0 = (r0 & 3) + 8 * (r0 >> 2);     // compile-time rows
        const int ro1 = (r1 & 3) + 8 * (r1 >> 2);
        zm = fmaxf(zm, (ro0 < thresh) ? u.v[r0] : NEGI);
        zm = fmaxf(zm, (ro1 < thresh) ? u.v[r1] : NEGI);
        const f32x2 h = u.h[pr];
        sA += h;
        qA += h * h;
      }
    }
  }
}

// One MFMA pair (both channel halves) + fold for a tile.
#define TILE_BODY(U0, U1, TFULL, THRESH, REM)                                   \
  {                                                                             \
    unsigned u0_ = (U0), u1_ = (U1);                                            \
    if (lane >= 32) { u0_ = 0u; u1_ = 0u; }  /* k-group 1 = zero pad */         \
    AF af;                                                                      \
    af.u[0] = u0_; af.u[1] = u1_; af.u[2] = 0; af.u[3] = 0;                     \
    {                                                                           \
      f32x16 c0 = __builtin_amdgcn_mfma_f32_32x32x16_bf16(af.v, bf0.v, z16, 0, 0, 0); \
      if (TFULL) fold_full(c0, zm0, zsA0, zqA0);                                \
      else       fold_mask(c0, (THRESH), (REM), zm0, zsA0, zqA0);               \
    }                                                                           \
    {                                                                           \
      f32x16 c1 = __builtin_amdgcn_mfma_f32_32x32x16_bf16(af.v, bf1.v, z16, 0, 0, 0); \
      if (TFULL) fold_full(c1, zm1, zsA1, zqA1);                                \
      else       fold_mask(c1, (THRESH), (REM), zm1, zsA1, zqA1);               \
    }                                                                           \
  }

// K1: r21 structure (LDS-free register A-fragments, prefetch, 4 static tiles,
// DPP wave-reduce, quad-skip fold) with packed-f32 zs/zq accumulation.
// Per-pillar epilogue (r7-verified):
//   ymax = zmax + b ; sum += zs + np*b ; sumsq += zq + b*(2*zs + np*b)
__global__ __launch_bounds__(256) void k1_mfma(
    const float4* __restrict__ feat, const int* __restrict__ npts,
    const int* __restrict__ coords, const float* __restrict__ W,
    float* __restrict__ ymax, float* __restrict__ partials, int nb) {
  const int lane = threadIdx.x & 63;
  const int wv   = threadIdx.x >> 6;
  const int wave_id = blockIdx.x * 4 + wv;
  const int nwaves  = nb * 4;
  const int rbase   = (lane >> 5) * 4;

  // per-channel weights, affine-folded: ce = (w0+w4+w7, w1+w5+w8, w2+w6, w3)
  float wr[9];
#pragma unroll
  for (int i = 0; i < 9; i++) wr[i] = W[lane * 9 + i];
  const float ce0 = wr[0] + wr[4] + wr[7];
  const float ce1 = wr[1] + wr[5] + wr[8];
  const float ce2 = wr[2] + wr[6];
  const float ce3 = wr[3];

  // B fragments: lane -> channel n*32+(lane&31), real k=0..3 in slots u0,u1
  AF bf0, bf1;
  {
    const unsigned p01 = pack_bf2(ce0, ce1);
    const unsigned p23 = pack_bf2(ce2, ce3);
    const int s0 = lane & 31, s1 = 32 + (lane & 31);
    unsigned b0a = (unsigned)__shfl((int)p01, s0);
    unsigned b0b = (unsigned)__shfl((int)p23, s0);
    unsigned b1a = (unsigned)__shfl((int)p01, s1);
    unsigned b1b = (unsigned)__shfl((int)p23, s1);
    if (lane >= 32) { b0a = b0b = b1a = b1b = 0; }
    bf0.u[0] = b0a; bf0.u[1] = b0b; bf0.u[2] = 0; bf0.u[3] = 0;
    bf1.u[0] = b1a; bf1.u[1] = b1b; bf1.u[2] = 0; bf1.u[3] = 0;
  }

  const f32x16 z16 = {0.f};
  float sum = 0.f, sumsq = 0.f;

  // prologue: load pillar wave_id
  int p = wave_id;
  float4 a0 = make_float4(0.f, 0.f, 0.f, 0.f), a1 = a0;
  int np = 1, cx = 0, cy = 0;
  if (p < P_TOT) {
    const float4* fp = feat + (size_t)p * NPT;
    a0 = fp[lane];
    if (lane < 36) a1 = fp[lane + 64];
    np = npts[p];
    cx = coords[p * 4 + 3];
    cy = coords[p * 4 + 2];
  }

  while (p < P_TOT) {
    const int pn = p + nwaves;
    float4 b0 = make_float4(0.f, 0.f, 0.f, 0.f), b1 = b0;
    int npn = 1, cxn = 0, cyn = 0;
    if (pn < P_TOT) {
      const float4* fpn = feat + (size_t)pn * NPT;
      b0 = fpn[lane];
      if (lane < 36) b1 = fpn[lane + 64];
      npn = npts[pn];
      cxn = coords[pn * 4 + 3];
      cyn = coords[pn * 4 + 2];
    }

    // pack to bf16, then mask (rows >= np become 0)
    unsigned pk0 = pack_bf2(a0.x, a0.y), pk1 = pack_bf2(a0.z, a0.w);
    unsigned pk2 = pack_bf2(a1.x, a1.y), pk3 = pack_bf2(a1.z, a1.w);
    if (lane >= np)      { pk0 = 0u; pk1 = 0u; }
    if (lane + 64 >= np) { pk2 = 0u; pk3 = 0u; }

    // cross-lane xyz sums from RAW rows via DPP (reference: ALL 100 rows / np)
    const float sax = wred_dpp(a0.x + a1.x);
    const float say = wred_dpp(a0.y + a1.y);
    const float saz = wred_dpp(a0.z + a1.z);
    const float inv = 1.f / (float)np;
    const float cxc = (float)cx * VXf + XOFFf;
    const float cyc = (float)cy * VYf + YOFFf;
    float b = wr[4] * (sax * inv);
    b = fmaf(wr[5], say * inv, b);
    b = fmaf(wr[6], saz * inv, b);
    b = fmaf(wr[7], cxc, b);
    b = fmaf(wr[8], cyc, b);
    b = -b;

    // z-loop: 4 static tiles, A-fragments from registers (no LDS)
    float zm0 = NEGI, zm1 = NEGI;
    f32x2 zsA0 = {0.f, 0.f}, zsA1 = {0.f, 0.f};
    f32x2 zqA0 = {0.f, 0.f}, zqA1 = {0.f, 0.f};

    TILE_BODY(pk0, pk1, (np >= 32), np - rbase, np);             // tile 0
    if (np > 32) {                                               // tile 1
      const unsigned s0 = (unsigned)__shfl_xor((int)pk0, 32);
      const unsigned s1 = (unsigned)__shfl_xor((int)pk1, 32);
      TILE_BODY(s0, s1, (np >= 64), np - 32 - rbase, np - 32);
    }
    if (np > 64) {                                               // tile 2
      TILE_BODY(pk2, pk3, (np >= 96), np - 64 - rbase, np - 64);
    }
    if (np > 96) {                                               // tile 3
      const unsigned s2 = (unsigned)__shfl_xor((int)pk2, 32);
      const unsigned s3 = (unsigned)__shfl_xor((int)pk3, 32);
      TILE_BODY(s2, s3, false, np - 96 - rbase, np - 96);
    }

    // collapse pair accumulators (same grouping as r21's s0/s1,q0/q1)
    float zs0 = zsA0.x + zsA0.y, zs1 = zsA1.x + zsA1.y;
    float zq0 = zqA0.x + zqA0.y, zq1 = zqA1.x + zqA1.y;

    // combine row-halves, pick this lane's channel half
    zm0 = fmaxf(zm0, __shfl_xor(zm0, 32));
    zm1 = fmaxf(zm1, __shfl_xor(zm1, 32));
    zs0 += __shfl_xor(zs0, 32);
    zs1 += __shfl_xor(zs1, 32);
    zq0 += __shfl_xor(zq0, 32);
    zq1 += __shfl_xor(zq1, 32);
    const float zm = (lane < 32) ? zm0 : zm1;   // channel = lane
    const float zs = (lane < 32) ? zs0 : zs1;
    const float zq = (lane < 32) ? zq0 : zq1;

    const float npf = (float)np;
    ymax[p * COUT + lane] = zm + b;
    sum   += zs + npf * b;
    sumsq += zq + b * fmaf(npf, b, 2.f * zs);

    p = pn;
    a0 = b0; a1 = b1; np = npn; cx = cxn; cy = cyn;
  }

  // block reduction: 64 sum rows, 64 sumsq rows
  __syncthreads();
  __shared__ float rs[4][64], rq[4][64];
  rs[wv][lane] = sum;
  rq[wv][lane] = sumsq;
  __syncthreads();
  const int t = threadIdx.x;
  if (t < 128) {
    const int c = t & 63;
    float v;
    if (t < 64) v = rs[0][c] + rs[1][c] + rs[2][c] + rs[3][c];
    else        v = rq[0][c] + rq[1][c] + rq[2][c] + rq[3][c];
    partials[(size_t)blockIdx.x * 128 + t] = v;   // coalesced, block-major
  }
}

// K2: 128 blocks (one per moment), 256 threads each -> TLP hides latency
__global__ __launch_bounds__(256) void k2_reduce(
    const float* __restrict__ partials, int nb, float* __restrict__ S) {
  const int m = blockIdx.x;
  float s = 0.f;
  for (int b = threadIdx.x; b < nb; b += 256) s += partials[(size_t)b * 128 + m];
  s = wred(s);
  __shared__ float t4[4];
  if ((threadIdx.x & 63) == 0) t4[threadIdx.x >> 6] = s;
  __syncthreads();
  if (threadIdx.x == 0) S[m] = t4[0] + t4[1] + t4[2] + t4[3];
}

// K3: finish in place on d_out. gamma==1 => scale>0, so max commutes with BN.
__global__ __launch_bounds__(256) void k3_finish(
    const int* __restrict__ npts, const float* __restrict__ S,
    const float* __restrict__ gamma, const float* __restrict__ beta,
    float* __restrict__ out) {
  const int c  = threadIdx.x & 63;
  const int wv = threadIdx.x >> 6;
  const int p  = blockIdx.x * 4 + wv;   // 7500*4 == 30000

  const float mean  = S[c] * INV_M;
  const float var   = S[64 + c] * INV_M - mean * mean;
  const float scale = gamma[c] * rsqrtf(var + 0.001f);
  const float shift = beta[c] - mean * scale;

  const int np = npts[p];
  float v = fmaf(scale, out[p * COUT + c], shift);
  if (np < NPT) v = fmaxf(v, shift);   // padded positions contribute relu(shift)
  out[p * COUT + c] = fmaxf(v, 0.f);
}

extern "C" void kernel_launch(void* const* d_in, const int* in_sizes, int n_in,
                              void* d_out, int out_size, void* d_ws, size_t ws_size,
                              hipStream_t stream) {
  const float4* feat  = (const float4*)d_in[0];
  const int*   npts   = (const int*)d_in[1];
  const int*   coords = (const int*)d_in[2];
  const float* W      = (const float*)d_in[3];
  const float* gamma  = (const float*)d_in[4];
  const float* beta   = (const float*)d_in[5];
  float* out = (float*)d_out;

  // nb=2048: exactly 8 blocks/CU uniform (r22's 1875 caused CU imbalance)
  int nb = 512;
  if (ws_size >= (size_t)(128 + 2048 * 128) * 4) nb = 2048;
  else if (ws_size >= (size_t)(128 + 1024 * 128) * 4) nb = 1024;

  float* S        = (float*)d_ws;   // 128 floats
  float* partials = S + 128;        // nb*128 floats, block-major

  k1_mfma<<<nb, 256, 0, stream>>>(feat, npts, coords, W, out, partials, nb);
  k2_reduce<<<128, 256, 0, stream>>>(partials, nb, S);
  k3_finish<<<P_TOT / 4, 256, 0, stream>>>(npts, S, gamma, beta, out);
}

// Round 25
// 39.693 us; speedup vs baseline: 1.0107x; 1.0023x over previous
//
#include <hip/hip_runtime.h>

#define P_TOT 30000
#define NPT   100
#define COUT  64

typedef __attribute__((ext_vector_type(8)))  short bf16x8;
typedef __attribute__((ext_vector_type(16))) float f32x16;

static constexpr float VXf   = 0.16f;
static constexpr float VYf   = 0.16f;
static constexpr float XOFFf = 0.08f;            // VX/2 + 0.0
static constexpr float YOFFf = 0.08f - 39.68f;   // VY/2 + y_min
static constexpr float INV_M = 1.0f / 3000000.0f; // 1/(P*N)
static constexpr float NEGI  = -3.0e38f;

__device__ inline float wred(float v) {           // cold paths (K2, epilogue)
#pragma unroll
  for (int d = 1; d < 64; d <<= 1) v += __shfl_xor(v, d);
  return v;
}

// Hot-path wave sum via DPP (canonical gfx9 reduce).
__device__ inline float wred_dpp(float v) {
  float t;
  t = __int_as_float(__builtin_amdgcn_update_dpp(0, __float_as_int(v), 0xB1, 0xF, 0xF, true));  v += t; // xor1
  t = __int_as_float(__builtin_amdgcn_update_dpp(0, __float_as_int(v), 0x4E, 0xF, 0xF, true));  v += t; // xor2
  t = __int_as_float(__builtin_amdgcn_update_dpp(0, __float_as_int(v), 0x141, 0xF, 0xF, true)); v += t; // row_half_mirror
  t = __int_as_float(__builtin_amdgcn_update_dpp(0, __float_as_int(v), 0x140, 0xF, 0xF, true)); v += t; // row_mirror
  t = __int_as_float(__builtin_amdgcn_update_dpp(0, __float_as_int(v), 0x142, 0xA, 0xF, true)); v += t; // bcast15
  t = __int_as_float(__builtin_amdgcn_update_dpp(0, __float_as_int(v), 0x143, 0xC, 0xF, true)); v += t; // bcast31
  return __int_as_float(__builtin_amdgcn_readlane(__float_as_int(v), 63));
}

// (bf16(hi) << 16) | bf16(lo)
__device__ inline unsigned pack_bf2(float lo, float hi) {
  return (__float_as_uint(hi) & 0xFFFF0000u) | (__float_as_uint(lo) >> 16);
}

union AF { bf16x8 v; unsigned u[4]; };

// Full-tile 3-op fold: max3-chain + add + fma (all rows valid).
__device__ inline void fold_full(const f32x16& c, float& zm, float& zs, float& zq) {
  float s0 = 0.f, s1 = 0.f, q0 = 0.f, q1 = 0.f;
#pragma unroll
  for (int r = 0; r < 8; ++r) {
    zm = fmaxf(fmaxf(zm, c[2 * r]), c[2 * r + 1]);
    s0 += c[2 * r];
    s1 += c[2 * r + 1];
    q0 = fmaf(c[2 * r], c[2 * r], q0);
    q1 = fmaf(c[2 * r + 1], c[2 * r + 1], q1);
  }
  zs += s0 + s1;
  zq += q0 + q1;
}

// Partial-tile fold, boundary-quad-only masking. Quad qd covers rows
// 8qd..8qd+7 (both lane halves; rbase in {0,4}).
//  - rem >= 8qd+8 : fully valid -> unmasked 3-op fold
//  - 8qd < rem    : boundary    -> per-value thresh mask on the MAX only
//                                  (pad rows are exactly 0 -> sums safe)
//  - else         : all-pad     -> skip
// Mask on max is REQUIRED: ymax adds b afterwards, so a zero entering the
// max would become a phantom value b (r24 bug).
__device__ inline void fold_part(const f32x16& c, int rem, int rbase,
                                 float& zm, float& zs, float& zq) {
  float s0 = 0.f, s1 = 0.f, q0 = 0.f, q1 = 0.f;
#pragma unroll
  for (int qd = 0; qd < 4; ++qd) {
    if (rem >= 8 * qd + 8) {          // wave-uniform: fully valid quad
#pragma unroll
      for (int r = 4 * qd; r < 4 * qd + 4; ++r) {
        if (r & 1) {
          zm = fmaxf(zm, c[r]);       // pairs folded below keep max3 density
          s1 += c[r];
          q1 = fmaf(c[r], c[r], q1);
        } else {
          zm = fmaxf(zm, c[r]);
          s0 += c[r];
          q0 = fmaf(c[r], c[r], q0);
        }
      }
    } else if (8 * qd < rem) {        // wave-uniform: boundary quad
      const int thresh = rem - rbase; // per-lane (rbase differs by half)
#pragma unroll
      for (int r = 4 * qd; r < 4 * qd + 4; ++r) {
        const int ro = (r & 3) + 8 * (r >> 2);        // compile-time row
        zm = fmaxf(zm, (ro < thresh) ? c[r] : NEGI);  // exclude pad rows
        if (r & 1) { s1 += c[r]; q1 = fmaf(c[r], c[r], q1); }
        else       { s0 += c[r]; q0 = fmaf(c[r], c[r], q0); }
      }
    }
  }
  zs += s0 + s1;
  zq += q0 + q1;
}

// One MFMA pair (both channel halves) + fold for a tile.
#define TILE_BODY(U0, U1, TFULL, REM)                                           \
  {                                                                             \
    unsigned u0_ = (U0), u1_ = (U1);                                            \
    if (lane >= 32) { u0_ = 0u; u1_ = 0u; }  /* k-group 1 = zero pad */         \
    AF af;                                                                      \
    af.u[0] = u0_; af.u[1] = u1_; af.u[2] = 0; af.u[3] = 0;                     \
    {                                                                           \
      f32x16 c0 = __builtin_amdgcn_mfma_f32_32x32x16_bf16(af.v, bf0.v, z16, 0, 0, 0); \
      if (TFULL) fold_full(c0, zm0, zs0, zq0);                                  \
      else       fold_part(c0, (REM), rbase, zm0, zs0, zq0);                    \
    }                                                                           \
    {                                                                           \
      f32x16 c1 = __builtin_amdgcn_mfma_f32_32x32x16_bf16(af.v, bf1.v, z16, 0, 0, 0); \
      if (TFULL) fold_full(c1, zm1, zs1, zq1);                                  \
      else       fold_part(c1, (REM), rbase, zm1, zs1, zq1);                    \
    }                                                                           \
  }

// Swap-trick half combine (verified): va stays local, vb is what the
// PARTNER lane needs -> one shfl per quantity instead of two.
#define COMBINE(OP, X0, X1, DST)                                                \
  {                                                                             \
    const float va = (lane < 32) ? (X0) : (X1);                                 \
    const float vb = (lane < 32) ? (X1) : (X0);                                 \
    DST = OP(va, __shfl_xor(vb, 32));                                           \
  }

// K1: r21 structure (LDS-free register A-fragments, prefetch, 4 static tiles,
// DPP wave-reduce, in-fold 3-op stats) + boundary-quad-only masking +
// swap-trick epilogue. Per-pillar epilogue (r7-verified):
//   ymax = zmax + b ; sum += zs + np*b ; sumsq += zq + b*(2*zs + np*b)
__global__ __launch_bounds__(256) void k1_mfma(
    const float4* __restrict__ feat, const int* __restrict__ npts,
    const int* __restrict__ coords, const float* __restrict__ W,
    float* __restrict__ ymax, float* __restrict__ partials, int nb) {
  const int lane = threadIdx.x & 63;
  const int wv   = threadIdx.x >> 6;
  const int wave_id = blockIdx.x * 4 + wv;
  const int nwaves  = nb * 4;
  const int rbase   = (lane >> 5) * 4;

  // per-channel weights, affine-folded: ce = (w0+w4+w7, w1+w5+w8, w2+w6, w3)
  float wr[9];
#pragma unroll
  for (int i = 0; i < 9; i++) wr[i] = W[lane * 9 + i];
  const float ce0 = wr[0] + wr[4] + wr[7];
  const float ce1 = wr[1] + wr[5] + wr[8];
  const float ce2 = wr[2] + wr[6];
  const float ce3 = wr[3];

  // B fragments: lane -> channel n*32+(lane&31), real k=0..3 in slots u0,u1
  AF bf0, bf1;
  {
    const unsigned p01 = pack_bf2(ce0, ce1);
    const unsigned p23 = pack_bf2(ce2, ce3);
    const int s0 = lane & 31, s1 = 32 + (lane & 31);
    unsigned b0a = (unsigned)__shfl((int)p01, s0);
    unsigned b0b = (unsigned)__shfl((int)p23, s0);
    unsigned b1a = (unsigned)__shfl((int)p01, s1);
    unsigned b1b = (unsigned)__shfl((int)p23, s1);
    if (lane >= 32) { b0a = b0b = b1a = b1b = 0; }
    bf0.u[0] = b0a; bf0.u[1] = b0b; bf0.u[2] = 0; bf0.u[3] = 0;
    bf1.u[0] = b1a; bf1.u[1] = b1b; bf1.u[2] = 0; bf1.u[3] = 0;
  }

  const f32x16 z16 = {0.f};
  float sum = 0.f, sumsq = 0.f;

  // prologue: load pillar wave_id
  int p = wave_id;
  float4 a0 = make_float4(0.f, 0.f, 0.f, 0.f), a1 = a0;
  int np = 1, cx = 0, cy = 0;
  if (p < P_TOT) {
    const float4* fp = feat + (size_t)p * NPT;
    a0 = fp[lane];
    if (lane < 36) a1 = fp[lane + 64];
    np = npts[p];
    cx = coords[p * 4 + 3];
    cy = coords[p * 4 + 2];
  }

  while (p < P_TOT) {
    const int pn = p + nwaves;
    float4 b0 = make_float4(0.f, 0.f, 0.f, 0.f), b1 = b0;
    int npn = 1, cxn = 0, cyn = 0;
    if (pn < P_TOT) {
      const float4* fpn = feat + (size_t)pn * NPT;
      b0 = fpn[lane];
      if (lane < 36) b1 = fpn[lane + 64];
      npn = npts[pn];
      cxn = coords[pn * 4 + 3];
      cyn = coords[pn * 4 + 2];
    }

    // pack to bf16, then mask (rows >= np become 0)
    unsigned pk0 = pack_bf2(a0.x, a0.y), pk1 = pack_bf2(a0.z, a0.w);
    unsigned pk2 = pack_bf2(a1.x, a1.y), pk3 = pack_bf2(a1.z, a1.w);
    if (lane >= np)      { pk0 = 0u; pk1 = 0u; }
    if (lane + 64 >= np) { pk2 = 0u; pk3 = 0u; }

    // cross-lane xyz sums from RAW rows via DPP (reference: ALL 100 rows / np)
    const float sax = wred_dpp(a0.x + a1.x);
    const float say = wred_dpp(a0.y + a1.y);
    const float saz = wred_dpp(a0.z + a1.z);
    const float inv = 1.f / (float)np;
    const float cxc = (float)cx * VXf + XOFFf;
    const float cyc = (float)cy * VYf + YOFFf;
    float b = wr[4] * (sax * inv);
    b = fmaf(wr[5], say * inv, b);
    b = fmaf(wr[6], saz * inv, b);
    b = fmaf(wr[7], cxc, b);
    b = fmaf(wr[8], cyc, b);
    b = -b;

    // z-loop: 4 static tiles, A-fragments from registers (no LDS)
    float zm0 = NEGI, zm1 = NEGI;
    float zs0 = 0.f, zs1 = 0.f, zq0 = 0.f, zq1 = 0.f;

    TILE_BODY(pk0, pk1, (np >= 32), np);                         // tile 0
    if (np > 32) {                                               // tile 1
      const unsigned s0 = (unsigned)__shfl_xor((int)pk0, 32);
      const unsigned s1 = (unsigned)__shfl_xor((int)pk1, 32);
      TILE_BODY(s0, s1, (np >= 64), np - 32);
    }
    if (np > 64) {                                               // tile 2
      TILE_BODY(pk2, pk3, (np >= 96), np - 64);
    }
    if (np > 96) {                                               // tile 3
      const unsigned s2 = (unsigned)__shfl_xor((int)pk2, 32);
      const unsigned s3 = (unsigned)__shfl_xor((int)pk3, 32);
      TILE_BODY(s2, s3, false, np - 96);
    }

    // combine row-halves with one shfl each, pick this lane's channel half
    float zm, zs, zq;
    COMBINE(fmaxf, zm0, zm1, zm);
    #define FADD(a, bb) ((a) + (bb))
    COMBINE(FADD, zs0, zs1, zs);
    COMBINE(FADD, zq0, zq1, zq);
    #undef FADD

    const float npf = (float)np;
    ymax[p * COUT + lane] = zm + b;
    sum   += zs + npf * b;
    sumsq += zq + b * fmaf(npf, b, 2.f * zs);

    p = pn;
    a0 = b0; a1 = b1; np = npn; cx = cxn; cy = cyn;
  }

  // block reduction: 64 sum rows, 64 sumsq rows
  __syncthreads();
  __shared__ float rs[4][64], rq[4][64];
  rs[wv][lane] = sum;
  rq[wv][lane] = sumsq;
  __syncthreads();
  const int t = threadIdx.x;
  if (t < 128) {
    const int c = t & 63;
    float v;
    if (t < 64) v = rs[0][c] + rs[1][c] + rs[2][c] + rs[3][c];
    else        v = rq[0][c] + rq[1][c] + rq[2][c] + rq[3][c];
    partials[(size_t)blockIdx.x * 128 + t] = v;   // coalesced, block-major
  }
}

// K2: 128 blocks (one per moment), 256 threads each -> TLP hides latency
__global__ __launch_bounds__(256) void k2_reduce(
    const float* __restrict__ partials, int nb, float* __restrict__ S) {
  const int m = blockIdx.x;
  float s = 0.f;
  for (int b = threadIdx.x; b < nb; b += 256) s += partials[(size_t)b * 128 + m];
  s = wred(s);
  __shared__ float t4[4];
  if ((threadIdx.x & 63) == 0) t4[threadIdx.x >> 6] = s;
  __syncthreads();
  if (threadIdx.x == 0) S[m] = t4[0] + t4[1] + t4[2] + t4[3];
}

// K3: finish in place on d_out. gamma==1 => scale>0, so max commutes with BN.
__global__ __launch_bounds__(256) void k3_finish(
    const int* __restrict__ npts, const float* __restrict__ S,
    const float* __restrict__ gamma, const float* __restrict__ beta,
    float* __restrict__ out) {
  const int c  = threadIdx.x & 63;
  const int wv = threadIdx.x >> 6;
  const int p  = blockIdx.x * 4 + wv;   // 7500*4 == 30000

  const float mean  = S[c] * INV_M;
  const float var   = S[64 + c] * INV_M - mean * mean;
  const float scale = gamma[c] * rsqrtf(var + 0.001f);
  const float shift = beta[c] - mean * scale;

  const int np = npts[p];
  float v = fmaf(scale, out[p * COUT + c], shift);
  if (np < NPT) v = fmaxf(v, shift);   // padded positions contribute relu(shift)
  out[p * COUT + c] = fmaxf(v, 0.f);
}

extern "C" void kernel_launch(void* const* d_in, const int* in_sizes, int n_in,
                              void* d_out, int out_size, void* d_ws, size_t ws_size,
                              hipStream_t stream) {
  const float4* feat  = (const float4*)d_in[0];
  const int*   npts   = (const int*)d_in[1];
  const int*   coords = (const int*)d_in[2];
  const float* W      = (const float*)d_in[3];
  const float* gamma  = (const float*)d_in[4];
  const float* beta   = (const float*)d_in[5];
  float* out = (float*)d_out;

  // nb=2048: exactly 8 blocks/CU uniform
  int nb = 512;
  if (ws_size >= (size_t)(128 + 2048 * 128) * 4) nb = 2048;
  else if (ws_size >= (size_t)(128 + 1024 * 128) * 4) nb = 1024;

  float* S        = (float*)d_ws;   // 128 floats
  float* partials = S + 128;        // nb*128 floats, block-major

  k1_mfma<<<nb, 256, 0, stream>>>(feat, npts, coords, W, out, partials, nb);
  k2_reduce<<<128, 256, 0, stream>>>(partials, nb, S);
  k3_finish<<<P_TOT / 4, 256, 0, stream>>>(npts, S, gamma, beta, out);
}

// Round 26
// 38.316 us; speedup vs baseline: 1.0471x; 1.0359x over previous
//
#include <hip/hip_runtime.h>

#define P_TOT 30000
#define NPT   100
#define COUT  64

typedef __attribute__((ext_vector_type(8)))  short bf16x8;
typedef __attribute__((ext_vector_type(16))) float f32x16;

static constexpr float VXf   = 0.16f;
static constexpr float VYf   = 0.16f;
static constexpr float XOFFf = 0.08f;            // VX/2 + 0.0
static constexpr float YOFFf = 0.08f - 39.68f;   // VY/2 + y_min
static constexpr float INV_M = 1.0f / 3000000.0f; // 1/(P*N)
static constexpr float NEGI  = -3.0e38f;

__device__ inline float wred(float v) {           // cold paths (K2, epilogue)
#pragma unroll
  for (int d = 1; d < 64; d <<= 1) v += __shfl_xor(v, d);
  return v;
}

// Hot-path wave sum via DPP (canonical gfx9 reduce):
// quad_perm xor1, xor2; row_half_mirror; row_mirror; bcast15->rows1,3;
// bcast31->rows2,3; total lands in lane 63; readlane broadcasts via SGPR.
__device__ inline float wred_dpp(float v) {
  float t;
  t = __int_as_float(__builtin_amdgcn_update_dpp(0, __float_as_int(v), 0xB1, 0xF, 0xF, true));  v += t; // xor1
  t = __int_as_float(__builtin_amdgcn_update_dpp(0, __float_as_int(v), 0x4E, 0xF, 0xF, true));  v += t; // xor2
  t = __int_as_float(__builtin_amdgcn_update_dpp(0, __float_as_int(v), 0x141, 0xF, 0xF, true)); v += t; // row_half_mirror
  t = __int_as_float(__builtin_amdgcn_update_dpp(0, __float_as_int(v), 0x140, 0xF, 0xF, true)); v += t; // row_mirror
  t = __int_as_float(__builtin_amdgcn_update_dpp(0, __float_as_int(v), 0x142, 0xA, 0xF, true)); v += t; // bcast15
  t = __int_as_float(__builtin_amdgcn_update_dpp(0, __float_as_int(v), 0x143, 0xC, 0xF, true)); v += t; // bcast31
  return __int_as_float(__builtin_amdgcn_readlane(__float_as_int(v), 63));
}

// (bf16(hi) << 16) | bf16(lo)
__device__ inline unsigned pack_bf2(float lo, float hi) {
  return (__float_as_uint(hi) & 0xFFFF0000u) | (__float_as_uint(lo) >> 16);
}

union AF { bf16x8 v; unsigned u[4]; };

// 3-op fold: max + add + fma(sumsq). Paired partials break the add chains.
__device__ inline void fold_full(const f32x16& c, float& zm, float& zs, float& zq) {
  float s0 = 0.f, s1 = 0.f, q0 = 0.f, q1 = 0.f;
#pragma unroll
  for (int r = 0; r < 8; ++r) {
    zm = fmaxf(fmaxf(zm, c[2 * r]), c[2 * r + 1]);
    s0 += c[2 * r];
    s1 += c[2 * r + 1];
    q0 = fmaf(c[2 * r], c[2 * r], q0);
    q1 = fmaf(c[2 * r + 1], c[2 * r + 1], q1);
  }
  zs += s0 + s1;
  zq += q0 + q1;
}

// Masked fold with quad-skip: C-reg quad qd covers rows 8qd..8qd+7 (both
// lane halves); skip it entirely (uniform branch) when 8qd >= rem.
// Pad rows are exactly 0 -> skipping them is safe for zs/zq too.
__device__ inline void fold_mask(const f32x16& c, int thresh, int rem,
                                 float& zm, float& zs, float& zq) {
  float s0 = 0.f, s1 = 0.f, q0 = 0.f, q1 = 0.f;
#pragma unroll
  for (int qd = 0; qd < 4; ++qd) {
    if (8 * qd < rem) {     // wave-uniform (rem = np - 32t)
#pragma unroll
      for (int r = 4 * qd; r < 4 * qd + 4; ++r) {
        const int ro = (r & 3) + 8 * (r >> 2);        // compile-time row offset
        zm = fmaxf(zm, (ro < thresh) ? c[r] : NEGI);  // exclude zero pad rows
        if (r & 1) { s1 += c[r]; q1 = fmaf(c[r], c[r], q1); }
        else       { s0 += c[r]; q0 = fmaf(c[r], c[r], q0); }
      }
    }
  }
  zs += s0 + s1;
  zq += q0 + q1;
}

// One MFMA pair (both channel halves) + fold for a tile.
#define TILE_BODY(U0, U1, TFULL, THRESH, REM)                                   \
  {                                                                             \
    unsigned u0_ = (U0), u1_ = (U1);                                            \
    if (lane >= 32) { u0_ = 0u; u1_ = 0u; }  /* k-group 1 = zero pad */         \
    AF af;                                                                      \
    af.u[0] = u0_; af.u[1] = u1_; af.u[2] = 0; af.u[3] = 0;                     \
    {                                                                           \
      f32x16 c0 = __builtin_amdgcn_mfma_f32_32x32x16_bf16(af.v, bf0.v, z16, 0, 0, 0); \
      if (TFULL) fold_full(c0, zm0, zs0, zq0);                                  \
      else       fold_mask(c0, (THRESH), (REM), zm0, zs0, zq0);                 \
    }                                                                           \
    {                                                                           \
      f32x16 c1 = __builtin_amdgcn_mfma_f32_32x32x16_bf16(af.v, bf1.v, z16, 0, 0, 0); \
      if (TFULL) fold_full(c1, zm1, zs1, zq1);                                  \
      else       fold_mask(c1, (THRESH), (REM), zm1, zs1, zq1);                 \
    }                                                                           \
  }

// K1: LDS-free register A-fragments, prefetch, 4 static tiles, in-fold 3-op
// stats, DPP wave-reduce, quad-skip fold (best measured config, r21).
// Per-pillar epilogue (r7-verified):
//   ymax = zmax + b ; sum += zs + np*b ; sumsq += zq + b*(2*zs + np*b)
__global__ __launch_bounds__(256) void k1_mfma(
    const float4* __restrict__ feat, const int* __restrict__ npts,
    const int* __restrict__ coords, const float* __restrict__ W,
    float* __restrict__ ymax, float* __restrict__ partials, int nb) {
  const int lane = threadIdx.x & 63;
  const int wv   = threadIdx.x >> 6;
  const int wave_id = blockIdx.x * 4 + wv;
  const int nwaves  = nb * 4;
  const int rbase   = (lane >> 5) * 4;

  // per-channel weights, affine-folded: ce = (w0+w4+w7, w1+w5+w8, w2+w6, w3)
  float wr[9];
#pragma unroll
  for (int i = 0; i < 9; i++) wr[i] = W[lane * 9 + i];
  const float ce0 = wr[0] + wr[4] + wr[7];
  const float ce1 = wr[1] + wr[5] + wr[8];
  const float ce2 = wr[2] + wr[6];
  const float ce3 = wr[3];

  // B fragments: lane -> channel n*32+(lane&31), real k=0..3 in slots u0,u1
  AF bf0, bf1;
  {
    const unsigned p01 = pack_bf2(ce0, ce1);
    const unsigned p23 = pack_bf2(ce2, ce3);
    const int s0 = lane & 31, s1 = 32 + (lane & 31);
    unsigned b0a = (unsigned)__shfl((int)p01, s0);
    unsigned b0b = (unsigned)__shfl((int)p23, s0);
    unsigned b1a = (unsigned)__shfl((int)p01, s1);
    unsigned b1b = (unsigned)__shfl((int)p23, s1);
    if (lane >= 32) { b0a = b0b = b1a = b1b = 0; }
    bf0.u[0] = b0a; bf0.u[1] = b0b; bf0.u[2] = 0; bf0.u[3] = 0;
    bf1.u[0] = b1a; bf1.u[1] = b1b; bf1.u[2] = 0; bf1.u[3] = 0;
  }

  const f32x16 z16 = {0.f};
  float sum = 0.f, sumsq = 0.f;

  // prologue: load pillar wave_id
  int p = wave_id;
  float4 a0 = make_float4(0.f, 0.f, 0.f, 0.f), a1 = a0;
  int np = 1, cx = 0, cy = 0;
  if (p < P_TOT) {
    const float4* fp = feat + (size_t)p * NPT;
    a0 = fp[lane];
    if (lane < 36) a1 = fp[lane + 64];
    np = npts[p];
    cx = coords[p * 4 + 3];
    cy = coords[p * 4 + 2];
  }

  while (p < P_TOT) {
    const int pn = p + nwaves;
    float4 b0 = make_float4(0.f, 0.f, 0.f, 0.f), b1 = b0;
    int npn = 1, cxn = 0, cyn = 0;
    if (pn < P_TOT) {
      const float4* fpn = feat + (size_t)pn * NPT;
      b0 = fpn[lane];
      if (lane < 36) b1 = fpn[lane + 64];
      npn = npts[pn];
      cxn = coords[pn * 4 + 3];
      cyn = coords[pn * 4 + 2];
    }

    // pack to bf16, then mask (rows >= np become 0)
    unsigned pk0 = pack_bf2(a0.x, a0.y), pk1 = pack_bf2(a0.z, a0.w);
    unsigned pk2 = pack_bf2(a1.x, a1.y), pk3 = pack_bf2(a1.z, a1.w);
    if (lane >= np)      { pk0 = 0u; pk1 = 0u; }
    if (lane + 64 >= np) { pk2 = 0u; pk3 = 0u; }

    // cross-lane xyz sums from RAW rows via DPP (reference: ALL 100 rows / np)
    const float sax = wred_dpp(a0.x + a1.x);
    const float say = wred_dpp(a0.y + a1.y);
    const float saz = wred_dpp(a0.z + a1.z);
    const float inv = 1.f / (float)np;
    const float cxc = (float)cx * VXf + XOFFf;
    const float cyc = (float)cy * VYf + YOFFf;
    float b = wr[4] * (sax * inv);
    b = fmaf(wr[5], say * inv, b);
    b = fmaf(wr[6], saz * inv, b);
    b = fmaf(wr[7], cxc, b);
    b = fmaf(wr[8], cyc, b);
    b = -b;

    // z-loop: 4 static tiles, A-fragments from registers (no LDS)
    float zm0 = NEGI, zm1 = NEGI;
    float zs0 = 0.f, zs1 = 0.f, zq0 = 0.f, zq1 = 0.f;

    TILE_BODY(pk0, pk1, (np >= 32), np - rbase, np);             // tile 0
    if (np > 32) {                                               // tile 1
      const unsigned s0 = (unsigned)__shfl_xor((int)pk0, 32);
      const unsigned s1 = (unsigned)__shfl_xor((int)pk1, 32);
      TILE_BODY(s0, s1, (np >= 64), np - 32 - rbase, np - 32);
    }
    if (np > 64) {                                               // tile 2
      TILE_BODY(pk2, pk3, (np >= 96), np - 64 - rbase, np - 64);
    }
    if (np > 96) {                                               // tile 3
      const unsigned s2 = (unsigned)__shfl_xor((int)pk2, 32);
      const unsigned s3 = (unsigned)__shfl_xor((int)pk3, 32);
      TILE_BODY(s2, s3, false, np - 96 - rbase, np - 96);
    }

    // combine row-halves, pick this lane's channel half
    zm0 = fmaxf(zm0, __shfl_xor(zm0, 32));
    zm1 = fmaxf(zm1, __shfl_xor(zm1, 32));
    zs0 += __shfl_xor(zs0, 32);
    zs1 += __shfl_xor(zs1, 32);
    zq0 += __shfl_xor(zq0, 32);
    zq1 += __shfl_xor(zq1, 32);
    const float zm = (lane < 32) ? zm0 : zm1;   // channel = lane
    const float zs = (lane < 32) ? zs0 : zs1;
    const float zq = (lane < 32) ? zq0 : zq1;

    const float npf = (float)np;
    ymax[p * COUT + lane] = zm + b;
    sum   += zs + npf * b;
    sumsq += zq + b * fmaf(npf, b, 2.f * zs);

    p = pn;
    a0 = b0; a1 = b1; np = npn; cx = cxn; cy = cyn;
  }

  // block reduction: 64 sum rows, 64 sumsq rows
  __syncthreads();
  __shared__ float rs[4][64], rq[4][64];
  rs[wv][lane] = sum;
  rq[wv][lane] = sumsq;
  __syncthreads();
  const int t = threadIdx.x;
  if (t < 128) {
    const int c = t & 63;
    float v;
    if (t < 64) v = rs[0][c] + rs[1][c] + rs[2][c] + rs[3][c];
    else        v = rq[0][c] + rq[1][c] + rq[2][c] + rq[3][c];
    partials[(size_t)blockIdx.x * 128 + t] = v;   // coalesced, block-major
  }
}

// K2: 128 blocks (one per moment), 256 threads each -> TLP hides latency
__global__ __launch_bounds__(256) void k2_reduce(
    const float* __restrict__ partials, int nb, float* __restrict__ S) {
  const int m = blockIdx.x;
  float s = 0.f;
  for (int b = threadIdx.x; b < nb; b += 256) s += partials[(size_t)b * 128 + m];
  s = wred(s);
  __shared__ float t4[4];
  if ((threadIdx.x & 63) == 0) t4[threadIdx.x >> 6] = s;
  __syncthreads();
  if (threadIdx.x == 0) S[m] = t4[0] + t4[1] + t4[2] + t4[3];
}

// K3: finish in place on d_out. gamma==1 => scale>0, so max commutes with BN.
__global__ __launch_bounds__(256) void k3_finish(
    const int* __restrict__ npts, const float* __restrict__ S,
    const float* __restrict__ gamma, const float* __restrict__ beta,
    float* __restrict__ out) {
  const int c  = threadIdx.x & 63;
  const int wv = threadIdx.x >> 6;
  const int p  = blockIdx.x * 4 + wv;   // 7500*4 == 30000

  const float mean  = S[c] * INV_M;
  const float var   = S[64 + c] * INV_M - mean * mean;
  const float scale = gamma[c] * rsqrtf(var + 0.001f);
  const float shift = beta[c] - mean * scale;

  const int np = npts[p];
  float v = fmaf(scale, out[p * COUT + c], shift);
  if (np < NPT) v = fmaxf(v, shift);   // padded positions contribute relu(shift)
  out[p * COUT + c] = fmaxf(v, 0.f);
}

extern "C" void kernel_launch(void* const* d_in, const int* in_sizes, int n_in,
                              void* d_out, int out_size, void* d_ws, size_t ws_size,
                              hipStream_t stream) {
  const float4* feat  = (const float4*)d_in[0];
  const int*   npts   = (const int*)d_in[1];
  const int*   coords = (const int*)d_in[2];
  const float* W      = (const float*)d_in[3];
  const float* gamma  = (const float*)d_in[4];
  const float* beta   = (const float*)d_in[5];
  float* out = (float*)d_out;

  // nb=2048: exactly 8 blocks/CU uniform
  int nb = 512;
  if (ws_size >= (size_t)(128 + 2048 * 128) * 4) nb = 2048;
  else if (ws_size >= (size_t)(128 + 1024 * 128) * 4) nb = 1024;

  float* S        = (float*)d_ws;   // 128 floats
  float* partials = S + 128;        // nb*128 floats, block-major

  k1_mfma<<<nb, 256, 0, stream>>>(feat, npts, coords, W, out, partials, nb);
  k2_reduce<<<128, 256, 0, stream>>>(partials, nb, S);
  k3_finish<<<P_TOT / 4, 256, 0, stream>>>(npts, S, gamma, beta, out);
}